// Round 1
// baseline (16.898 us; speedup 1.0000x reference)
//
#include <hip/hip_runtime.h>

// SAGraphPooling collapses analytically:
//   softmax over a size-1 axis == 1.0  ->  scoring is all-ones
//   stable top_k of all-equal values   ->  keep_indices = [0..1023]
// Outputs are pure slices:
//   Xs_out      = Xs[:, :1024, :]        [8,1024,128]
//   As_out      = As[:, :1024, :1024]    [8,1024,1024]
//   keep_values = ones                   [8,1024]
// => memory-bound float4 slice-copy, ~75.5 MB HBM traffic.

constexpr int B_   = 8;
constexpr int N_   = 2048;
constexpr int F_   = 128;
constexpr int KEEP = 1024;

// region sizes in float4 units
constexpr int R0 = B_ * KEEP * F_ / 4;     // 262144   (Xs_out)
constexpr int R1 = B_ * KEEP * KEEP / 4;   // 2097152  (As_out)
constexpr int R2 = B_ * KEEP / 4;          // 2048     (keep_values)
constexpr int TOTAL = R0 + R1 + R2;        // 2361344

__global__ void sag_pool_slice_copy(const float4* __restrict__ Xs,
                                    const float4* __restrict__ As,
                                    float4* __restrict__ out) {
    const int stride = gridDim.x * blockDim.x;
    for (int v = blockIdx.x * blockDim.x + threadIdx.x; v < TOTAL; v += stride) {
        if (v < R0) {
            // Xs_out: per batch, first KEEP rows of Xs are contiguous
            const int b   = v >> 15;        // / (KEEP*F/4 = 32768)
            const int rem = v & 32767;
            out[v] = Xs[b * (N_ * F_ / 4) + rem];   // N_*F_/4 = 65536
        } else if (v < R0 + R1) {
            // As_out: first KEEP cols of each of the first KEEP rows per batch
            const int u   = v - R0;
            const int b   = u >> 18;        // / (KEEP*KEEP/4 = 262144)
            const int rem = u & 262143;
            const int row = rem >> 8;       // / (KEEP/4 = 256)
            const int cv  = rem & 255;
            out[v] = As[b * (N_ * N_ / 4) + row * (N_ / 4) + cv]; // N_*N_/4=1048576, N_/4=512
        } else {
            out[v] = make_float4(1.0f, 1.0f, 1.0f, 1.0f);
        }
    }
}

extern "C" void kernel_launch(void* const* d_in, const int* in_sizes, int n_in,
                              void* d_out, int out_size, void* d_ws, size_t ws_size,
                              hipStream_t stream) {
    const float4* Xs = (const float4*)d_in[0];
    const float4* As = (const float4*)d_in[1];
    // d_in[2] (w0) is dead: softmax over size-1 axis is identically 1.
    float4* out = (float4*)d_out;

    const int block = 256;
    const int grid  = 2048;   // grid-stride; ~9 float4 per thread
    sag_pool_slice_copy<<<grid, block, 0, stream>>>(Xs, As, out);
}

// Round 3
// 15.684 us; speedup vs baseline: 1.0774x; 1.0774x over previous
//
#include <hip/hip_runtime.h>

// SAGraphPooling collapses analytically:
//   softmax over a size-1 axis == 1.0  ->  scoring is all-ones
//   stable top_k of all-equal values   ->  keep_indices = [0..1023]
// Outputs are pure slices:
//   Xs_out      = Xs[:, :1024, :]        [8,1024,128]
//   As_out      = As[:, :1024, :1024]    [8,1024,1024]
//   keep_values = ones                   [8,1024]
// => memory-bound float4 slice-copy, ~72.6 MB HBM traffic.
//
// One vec4 per thread, no loop. Region boundaries (R0, R0+R1) are exact
// multiples of 256 => the 3-way branch is block-uniform, zero divergence.
// Native clang vector type (not HIP float4) so nontemporal builtins accept it.

typedef float f32x4 __attribute__((ext_vector_type(4)));

constexpr int B_   = 8;
constexpr int N_   = 2048;
constexpr int F_   = 128;
constexpr int KEEP = 1024;

// region sizes in f32x4 units
constexpr int R0 = B_ * KEEP * F_ / 4;     // 262144   (Xs_out)  = 1024 blocks of 256
constexpr int R1 = B_ * KEEP * KEEP / 4;   // 2097152  (As_out)  = 8192 blocks
constexpr int R2 = B_ * KEEP / 4;          // 2048     (keep_values) = 8 blocks
constexpr int TOTAL = R0 + R1 + R2;        // 2361344  = 9224 * 256 exactly

__global__ __launch_bounds__(256) void sag_pool_slice_copy(
        const f32x4* __restrict__ Xs,
        const f32x4* __restrict__ As,
        f32x4* __restrict__ out) {
    const int v = blockIdx.x * 256 + threadIdx.x;
    if (v < R0) {
        // Xs_out: per batch, first KEEP rows of Xs are contiguous
        const int b   = v >> 15;        // / (KEEP*F/4 = 32768)
        const int rem = v & 32767;
        const f32x4 val = __builtin_nontemporal_load(&Xs[b * (N_ * F_ / 4) + rem]);
        __builtin_nontemporal_store(val, &out[v]);
    } else if (v < R0 + R1) {
        // As_out: first KEEP cols of each of the first KEEP rows per batch
        const int u   = v - R0;
        const int b   = u >> 18;        // / (KEEP*KEEP/4 = 262144)
        const int rem = u & 262143;
        const int row = rem >> 8;       // / (KEEP/4 = 256)
        const int cv  = rem & 255;
        const f32x4 val = __builtin_nontemporal_load(
            &As[b * (N_ * N_ / 4) + row * (N_ / 4) + cv]);  // strides 1048576, 512
        __builtin_nontemporal_store(val, &out[v]);
    } else {
        const f32x4 ones = {1.0f, 1.0f, 1.0f, 1.0f};
        __builtin_nontemporal_store(ones, &out[v]);
    }
}

extern "C" void kernel_launch(void* const* d_in, const int* in_sizes, int n_in,
                              void* d_out, int out_size, void* d_ws, size_t ws_size,
                              hipStream_t stream) {
    const f32x4* Xs = (const f32x4*)d_in[0];
    const f32x4* As = (const f32x4*)d_in[1];
    // d_in[2] (w0) is dead: softmax over size-1 axis is identically 1.
    f32x4* out = (f32x4*)d_out;

    sag_pool_slice_copy<<<TOTAL / 256, 256, 0, stream>>>(Xs, As, out);
}